// Round 7
// baseline (184.553 us; speedup 1.0000x reference)
//
#include <hip/hip_runtime.h>

#define DIM 160
#define TW 32
#define TH 16
#define RROWS 22
#define CHUNK 16
#define NCHUNK 10             // 160/CHUNK
#define NTOT 8192000.0f       // 2 * 160^3
#define EPS_S 13841.287f      // 1e-6 * 343^4
#define PLANE (DIM * DIM)

__device__ __forceinline__ float lncc_term(float SI, float SJ, float SI2,
                                           float SJ2, float SIJ)
{
    float cross = fmaf(SIJ, 343.f, -(SI * SJ));
    float vI    = fmaf(SI2, 343.f, -(SI * SI));
    float vJ    = fmaf(SJ2, 343.f, -(SJ * SJ));
    float den   = fmaf(vI, vJ, EPS_S);
    return cross * cross * __builtin_amdgcn_rcpf(den);
}

__global__ __launch_bounds__(256, 3) void lncc_fused_kernel(
    const float* __restrict__ I,
    const float* __restrict__ J,
    float* __restrict__ out)
{
    __shared__ __align__(16) float rs[2][5][RROWS][TW];   // 28,160 B double-buffered
    __shared__ float wsum[4];

    const int tid = threadIdx.x;
    const int tx = tid & 15;            // col stage: w-pair
    const int ty = tid >> 4;            // col stage: h
    const int rr = tid >> 3;            // row stage: row (active < 22)
    const int cc = (tid & 7) * 4;       // row stage: 4-col group
    const bool rowActive = (rr < RROWS);

    const int tw0 = blockIdx.x * TW;
    const int th0 = blockIdx.y * TH;
    const int bz  = blockIdx.z;
    const int b   = bz / NCHUNK;
    const int z0  = (bz - b * NCHUNK) * CHUNK;

    const float* Ib = I + (size_t)b * DIM * PLANE;
    const float* Jb = J + (size_t)b * DIM * PLANE;

    // clamped addresses + value masks: every step is branch-uniform straight-line
    const int gh  = th0 + rr - 3;
    const int ghc = min(max(gh, 0), DIM - 1);
    const bool hv = rowActive && (gh == ghc);
    const int gw0 = tw0 + cc - 4;
    const bool ok0 = ((unsigned)gw0       <= (unsigned)(DIM - 4));
    const bool ok1 = ((unsigned)(gw0 + 4) <= (unsigned)(DIM - 4));
    const bool ok2 = ((unsigned)(gw0 + 8) <= (unsigned)(DIM - 4));
    const int o0 = min(max(gw0,     0), DIM - 4);
    const int o1 = min(max(gw0 + 4, 0), DIM - 4);
    const int o2 = min(max(gw0 + 8, 0), DIM - 4);
    const int rowoff = ghc * DIM;

    // z-ring of 2D box sums, slot = step % 7 (static via unroll)
    float rngx[5][7], rngy[5][7], Sx[5], Sy[5];
#pragma unroll
    for (int f = 0; f < 5; ++f) {
        Sx[f] = 0.f; Sy[f] = 0.f;
#pragma unroll
        for (int k = 0; k < 7; ++k) { rngx[f][k] = 0.f; rngy[f][k] = 0.f; }
    }
    float acc = 0.f;

    // prefetch buffer (single, reused: consumed fully before re-issue)
    float4 A0, A1, A2, B0, B1, B2;
    int zin = z0 - 3;
    {   // prologue: load first slice (clamped)
        const int zc = min(max(zin, 0), DIM - 1);
        const float* Ip = Ib + zc * PLANE + rowoff;
        const float* Jp = Jb + zc * PLANE + rowoff;
        if (rowActive) {
            A0 = *(const float4*)(Ip + o0); A1 = *(const float4*)(Ip + o1); A2 = *(const float4*)(Ip + o2);
            B0 = *(const float4*)(Jp + o0); B1 = *(const float4*)(Jp + o1); B2 = *(const float4*)(Jp + o2);
        }
    }
    int p = 0, s = 0;

#define STEP(SLOT) {                                                            \
    const float m = (hv && ((unsigned)zin < (unsigned)DIM)) ? 1.0f : 0.0f;      \
    if (rowActive) {                                                            \
        const float i1=ok0?A0.y:0.f, i2=ok0?A0.z:0.f, i3=ok0?A0.w:0.f;          \
        const float i4=ok1?A1.x:0.f, i5=ok1?A1.y:0.f, i6=ok1?A1.z:0.f, i7=ok1?A1.w:0.f; \
        const float i8=ok2?A2.x:0.f, i9=ok2?A2.y:0.f, iA=ok2?A2.z:0.f;          \
        const float j1=ok0?B0.y:0.f, j2=ok0?B0.z:0.f, j3=ok0?B0.w:0.f;          \
        const float j4=ok1?B1.x:0.f, j5=ok1?B1.y:0.f, j6=ok1?B1.z:0.f, j7=ok1?B1.w:0.f; \
        const float j8=ok2?B2.x:0.f, j9=ok2?B2.y:0.f, jA=ok2?B2.z:0.f;          \
        { float t = i1+i2+i3+i4+i5+i6+i7; const float w0=t;                     \
          t += i8-i1; const float w1=t; t += i9-i2; const float w2=t;           \
          t += iA-i3; const float w3=t;                                         \
          *(float4*)&rs[p][0][rr][cc] = make_float4(m*w0, m*w1, m*w2, m*w3); }  \
        { float t = j1+j2+j3+j4+j5+j6+j7; const float w0=t;                     \
          t += j8-j1; const float w1=t; t += j9-j2; const float w2=t;           \
          t += jA-j3; const float w3=t;                                         \
          *(float4*)&rs[p][1][rr][cc] = make_float4(m*w0, m*w1, m*w2, m*w3); }  \
        { float t = i1*i1; t=fmaf(i2,i2,t); t=fmaf(i3,i3,t); t=fmaf(i4,i4,t);   \
          t=fmaf(i5,i5,t); t=fmaf(i6,i6,t); t=fmaf(i7,i7,t); const float w0=t;  \
          t=fmaf(i8,i8,fmaf(-i1,i1,t)); const float w1=t;                       \
          t=fmaf(i9,i9,fmaf(-i2,i2,t)); const float w2=t;                       \
          t=fmaf(iA,iA,fmaf(-i3,i3,t)); const float w3=t;                       \
          *(float4*)&rs[p][2][rr][cc] = make_float4(m*w0, m*w1, m*w2, m*w3); }  \
        { float t = j1*j1; t=fmaf(j2,j2,t); t=fmaf(j3,j3,t); t=fmaf(j4,j4,t);   \
          t=fmaf(j5,j5,t); t=fmaf(j6,j6,t); t=fmaf(j7,j7,t); const float w0=t;  \
          t=fmaf(j8,j8,fmaf(-j1,j1,t)); const float w1=t;                       \
          t=fmaf(j9,j9,fmaf(-j2,j2,t)); const float w2=t;                       \
          t=fmaf(jA,jA,fmaf(-j3,j3,t)); const float w3=t;                       \
          *(float4*)&rs[p][3][rr][cc] = make_float4(m*w0, m*w1, m*w2, m*w3); }  \
        { float t = i1*j1; t=fmaf(i2,j2,t); t=fmaf(i3,j3,t); t=fmaf(i4,j4,t);   \
          t=fmaf(i5,j5,t); t=fmaf(i6,j6,t); t=fmaf(i7,j7,t); const float w0=t;  \
          t=fmaf(i8,j8,fmaf(-i1,j1,t)); const float w1=t;                       \
          t=fmaf(i9,j9,fmaf(-i2,j2,t)); const float w2=t;                       \
          t=fmaf(iA,jA,fmaf(-i3,j3,t)); const float w3=t;                       \
          *(float4*)&rs[p][4][rr][cc] = make_float4(m*w0, m*w1, m*w2, m*w3); }  \
    }                                                                           \
    {   /* issue next slice's loads: in flight across the barrier (no vmcnt drain) */ \
        const int zn = min(max(zin + 1, 0), DIM - 1);   /* FIX: clamp below too */ \
        const float* Ip = Ib + zn * PLANE + rowoff;                             \
        const float* Jp = Jb + zn * PLANE + rowoff;                             \
        if (rowActive) {                                                        \
            A0 = *(const float4*)(Ip + o0); A1 = *(const float4*)(Ip + o1);     \
            A2 = *(const float4*)(Ip + o2);                                     \
            B0 = *(const float4*)(Jp + o0); B1 = *(const float4*)(Jp + o1);     \
            B2 = *(const float4*)(Jp + o2);                                     \
        }                                                                       \
    }                                                                           \
    asm volatile("s_waitcnt lgkmcnt(0)" ::: "memory");  /* ds_writes drained */ \
    __builtin_amdgcn_s_barrier();                       /* raw: no vmcnt(0) */  \
    __builtin_amdgcn_sched_barrier(0);                  /* pin col reads below */\
    {   float Cx[5] = {0,0,0,0,0}, Cy[5] = {0,0,0,0,0};                         \
        _Pragma("unroll")                                                       \
        for (int dr = 0; dr < 7; ++dr) {                                        \
            _Pragma("unroll")                                                   \
            for (int f = 0; f < 5; ++f) {                                       \
                const float2 v = *(const float2*)&rs[p][f][ty + dr][2 * tx];    \
                Cx[f] += v.x; Cy[f] += v.y;                                     \
            }                                                                   \
        }                                                                       \
        _Pragma("unroll")                                                       \
        for (int f = 0; f < 5; ++f) {                                           \
            Sx[f] += Cx[f] - rngx[f][SLOT]; rngx[f][SLOT] = Cx[f];              \
            Sy[f] += Cy[f] - rngy[f][SLOT]; rngy[f][SLOT] = Cy[f];              \
        }                                                                       \
        if (s >= 6) {                                                           \
            acc += lncc_term(Sx[0], Sx[1], Sx[2], Sx[3], Sx[4]);                \
            acc += lncc_term(Sy[0], Sy[1], Sy[2], Sy[3], Sy[4]);                \
        }                                                                       \
    }                                                                           \
    ++zin; ++s; p ^= 1; }

    // 22 steps = 3 x 7 (rolled, static ring slots) + 1 peeled (slot 0)
#pragma unroll 1
    for (int g = 0; g < 3; ++g) {
        STEP(0) STEP(1) STEP(2) STEP(3) STEP(4) STEP(5) STEP(6)
    }
    STEP(0)
#undef STEP

    // ---------- block reduce -> one atomic ----------
#pragma unroll
    for (int off = 32; off > 0; off >>= 1)
        acc += __shfl_down(acc, off, 64);
    if ((tid & 63) == 0) wsum[tid >> 6] = acc;
    __syncthreads();
    if (tid == 0) {
        float t = wsum[0] + wsum[1] + wsum[2] + wsum[3];
        atomicAdd(out, t * (-1.0f / NTOT));
    }
}

extern "C" void kernel_launch(void* const* d_in, const int* in_sizes, int n_in,
                              void* d_out, int out_size, void* d_ws, size_t ws_size,
                              hipStream_t stream) {
    const float* I = (const float*)d_in[0];
    const float* J = (const float*)d_in[1];
    float* out = (float*)d_out;

    hipMemsetAsync(out, 0, sizeof(float), stream);

    dim3 grid(DIM / TW, DIM / TH, 2 * NCHUNK);   // 5 x 10 x 20 = 1000 blocks
    dim3 block(256);
    lncc_fused_kernel<<<grid, block, 0, stream>>>(I, J, out);
}

// Round 9
// 129.039 us; speedup vs baseline: 1.4302x; 1.4302x over previous
//
#include <hip/hip_runtime.h>

#define DIM 160
#define TW 32
#define TH 32
#define RROWS 38              // TH + 6
#define SSTR 36               // padded LDS row stride (floats): 144B, 16B-aligned
#define FSTR (RROWS * SSTR)   // field stride in floats
#define CHUNK 16
#define NCHUNK 10             // 160/CHUNK
#define NTOT 8192000.0f       // 2 * 160^3
#define EPS_S 13841.287f      // 1e-6 * 343^4
#define PLANE (DIM * DIM)

__device__ __forceinline__ float lncc_term(float SI, float SJ, float SI2,
                                           float SJ2, float SIJ)
{
    float cross = fmaf(SIJ, 343.f, -(SI * SJ));
    float vI    = fmaf(SI2, 343.f, -(SI * SI));
    float vJ    = fmaf(SJ2, 343.f, -(SJ * SJ));
    float den   = fmaf(vI, vJ, EPS_S);
    return cross * cross * __builtin_amdgcn_rcpf(den);
}

// W-direction sliding 7-sums of {I, J, I2, J2, IJ} for 4 output cols; masked store.
__device__ __forceinline__ void row_cs(
    float4 A0, float4 A1, float4 A2,
    float4 B0, float4 B1, float4 B2,
    bool ok0, bool ok1, bool ok2, float m, float* dst)   // dst = &rs[p][0][rr][cc]
{
    const float i1=ok0?A0.y:0.f, i2=ok0?A0.z:0.f, i3=ok0?A0.w:0.f;
    const float i4=ok1?A1.x:0.f, i5=ok1?A1.y:0.f, i6=ok1?A1.z:0.f, i7=ok1?A1.w:0.f;
    const float i8=ok2?A2.x:0.f, i9=ok2?A2.y:0.f, iA=ok2?A2.z:0.f;
    const float j1=ok0?B0.y:0.f, j2=ok0?B0.z:0.f, j3=ok0?B0.w:0.f;
    const float j4=ok1?B1.x:0.f, j5=ok1?B1.y:0.f, j6=ok1?B1.z:0.f, j7=ok1?B1.w:0.f;
    const float j8=ok2?B2.x:0.f, j9=ok2?B2.y:0.f, jA=ok2?B2.z:0.f;
    { float t=i1+i2+i3+i4+i5+i6+i7; const float w0=t;
      t+=i8-i1; const float w1=t; t+=i9-i2; const float w2=t; t+=iA-i3; const float w3=t;
      *(float4*)(dst + 0*FSTR) = make_float4(m*w0,m*w1,m*w2,m*w3); }
    { float t=j1+j2+j3+j4+j5+j6+j7; const float w0=t;
      t+=j8-j1; const float w1=t; t+=j9-j2; const float w2=t; t+=jA-j3; const float w3=t;
      *(float4*)(dst + 1*FSTR) = make_float4(m*w0,m*w1,m*w2,m*w3); }
    { float t=i1*i1; t=fmaf(i2,i2,t); t=fmaf(i3,i3,t); t=fmaf(i4,i4,t);
      t=fmaf(i5,i5,t); t=fmaf(i6,i6,t); t=fmaf(i7,i7,t); const float w0=t;
      t=fmaf(i8,i8,fmaf(-i1,i1,t)); const float w1=t;
      t=fmaf(i9,i9,fmaf(-i2,i2,t)); const float w2=t;
      t=fmaf(iA,iA,fmaf(-i3,i3,t)); const float w3=t;
      *(float4*)(dst + 2*FSTR) = make_float4(m*w0,m*w1,m*w2,m*w3); }
    { float t=j1*j1; t=fmaf(j2,j2,t); t=fmaf(j3,j3,t); t=fmaf(j4,j4,t);
      t=fmaf(j5,j5,t); t=fmaf(j6,j6,t); t=fmaf(j7,j7,t); const float w0=t;
      t=fmaf(j8,j8,fmaf(-j1,j1,t)); const float w1=t;
      t=fmaf(j9,j9,fmaf(-j2,j2,t)); const float w2=t;
      t=fmaf(jA,jA,fmaf(-j3,j3,t)); const float w3=t;
      *(float4*)(dst + 3*FSTR) = make_float4(m*w0,m*w1,m*w2,m*w3); }
    { float t=i1*j1; t=fmaf(i2,j2,t); t=fmaf(i3,j3,t); t=fmaf(i4,j4,t);
      t=fmaf(i5,j5,t); t=fmaf(i6,j6,t); t=fmaf(i7,j7,t); const float w0=t;
      t=fmaf(i8,j8,fmaf(-i1,j1,t)); const float w1=t;
      t=fmaf(i9,j9,fmaf(-i2,j2,t)); const float w2=t;
      t=fmaf(iA,jA,fmaf(-i3,j3,t)); const float w3=t;
      *(float4*)(dst + 4*FSTR) = make_float4(m*w0,m*w1,m*w2,m*w3); }
}

__global__ __launch_bounds__(256, 2) void lncc_fused_kernel(
    const float* __restrict__ I,
    const float* __restrict__ J,
    float* __restrict__ out)
{
    __shared__ __align__(16) float rs[2][5][RROWS][SSTR];   // 54,720 B
    __shared__ float wsum[4];

    const int tid = threadIdx.x;
    const int tx = tid & 15;            // col stage: w-pair (cols 2tx, 2tx+1)
    const int ty = tid >> 4;            // col stage: h-pair (rows 2ty, 2ty+1)
    const int cg = tid & 7;             // row stage: 4-col group
    const int cc = cg * 4;
    const int rr0 = tid >> 3;           // row-stage item0: rows 0..31
    const int rr1 = 32 + rr0;           // item1: rows 32..37, only tid<48
    const bool t1v = (tid < 48);

    const int tw0 = blockIdx.x * TW;
    const int th0 = blockIdx.y * TH;
    const int bz  = blockIdx.z;
    const int b   = bz / NCHUNK;
    const int z0  = (bz - b * NCHUNK) * CHUNK;

    const float* Ib = I + (size_t)b * DIM * PLANE;
    const float* Jb = J + (size_t)b * DIM * PLANE;

    // W masks/clamps (shared by both items)
    const int gw0 = tw0 + cc - 4;
    const bool ok0 = ((unsigned)gw0       <= (unsigned)(DIM - 4));
    const bool ok1 = ((unsigned)(gw0 + 4) <= (unsigned)(DIM - 4));
    const bool ok2 = ((unsigned)(gw0 + 8) <= (unsigned)(DIM - 4));
    const int o0 = min(max(gw0,     0), DIM - 4);
    const int o1 = min(max(gw0 + 4, 0), DIM - 4);
    const int o2 = min(max(gw0 + 8, 0), DIM - 4);
    // H masks/clamps per item
    const int gh0 = th0 + rr0 - 3;
    const int gh0c = min(max(gh0, 0), DIM - 1);
    const bool hv0 = (gh0 == gh0c);
    const int row0off = gh0c * DIM;
    const int gh1 = th0 + rr1 - 3;
    const int gh1c = min(max(gh1, 0), DIM - 1);
    const bool hv1 = t1v && (gh1 == gh1c);
    const int row1off = gh1c * DIM;

    // z-ring of 2D box sums: [field][slot][output], slot = step % 7 (static)
    float rng[5][7][4], S[5][4];
#pragma unroll
    for (int f = 0; f < 5; ++f) {
#pragma unroll
        for (int o = 0; o < 4; ++o) S[f][o] = 0.f;
#pragma unroll
        for (int k = 0; k < 7; ++k) {
#pragma unroll
            for (int o = 0; o < 4; ++o) rng[f][k][o] = 0.f;
        }
    }
    float acc = 0.f;
    int p = 0, s = 0, zin = z0 - 3;

#define STEP(SLOT) {                                                            \
    const bool zvld = ((unsigned)zin < (unsigned)DIM);                          \
    const int zc = min(max(zin, 0), DIM - 1);                                   \
    const float* Ipl = Ib + (size_t)zc * PLANE;                                 \
    const float* Jpl = Jb + (size_t)zc * PLANE;                                 \
    {   /* row stage, item0 (all threads) */                                    \
        const float4 a0 = *(const float4*)(Ipl + row0off + o0);                 \
        const float4 a1 = *(const float4*)(Ipl + row0off + o1);                 \
        const float4 a2 = *(const float4*)(Ipl + row0off + o2);                 \
        const float4 b0 = *(const float4*)(Jpl + row0off + o0);                 \
        const float4 b1 = *(const float4*)(Jpl + row0off + o1);                 \
        const float4 b2 = *(const float4*)(Jpl + row0off + o2);                 \
        const float m0 = (hv0 && zvld) ? 1.f : 0.f;                             \
        row_cs(a0, a1, a2, b0, b1, b2, ok0, ok1, ok2, m0,                       \
               &rs[p][0][rr0][cc]);                                             \
    }                                                                           \
    if (t1v) {   /* row stage, item1 (rows 32..37) */                           \
        const float4 a0 = *(const float4*)(Ipl + row1off + o0);                 \
        const float4 a1 = *(const float4*)(Ipl + row1off + o1);                 \
        const float4 a2 = *(const float4*)(Ipl + row1off + o2);                 \
        const float4 b0 = *(const float4*)(Jpl + row1off + o0);                 \
        const float4 b1 = *(const float4*)(Jpl + row1off + o1);                 \
        const float4 b2 = *(const float4*)(Jpl + row1off + o2);                 \
        const float m1 = (hv1 && zvld) ? 1.f : 0.f;                             \
        row_cs(a0, a1, a2, b0, b1, b2, ok0, ok1, ok2, m1,                       \
               &rs[p][0][rr1][cc]);                                             \
    }                                                                           \
    __syncthreads();                                                            \
    {   /* col stage: rows 2ty..2ty+7 serve h-outputs 2ty (even) and 2ty+1 */   \
        float C[5][4];                                                          \
        _Pragma("unroll")                                                       \
        for (int f = 0; f < 5; ++f) {                                           \
            const float* rp = &rs[p][f][2 * ty][2 * tx];                        \
            const float2 v0 = *(const float2*)(rp + 0 * SSTR);                  \
            const float2 v1 = *(const float2*)(rp + 1 * SSTR);                  \
            const float2 v2 = *(const float2*)(rp + 2 * SSTR);                  \
            const float2 v3 = *(const float2*)(rp + 3 * SSTR);                  \
            const float2 v4 = *(const float2*)(rp + 4 * SSTR);                  \
            const float2 v5 = *(const float2*)(rp + 5 * SSTR);                  \
            const float2 v6 = *(const float2*)(rp + 6 * SSTR);                  \
            const float2 v7 = *(const float2*)(rp + 7 * SSTR);                  \
            const float cex = v0.x+v1.x+v2.x+v3.x+v4.x+v5.x+v6.x;               \
            const float cey = v0.y+v1.y+v2.y+v3.y+v4.y+v5.y+v6.y;               \
            C[f][0] = cex;              C[f][1] = cey;                          \
            C[f][2] = cex - v0.x + v7.x; C[f][3] = cey - v0.y + v7.y;           \
        }                                                                       \
        _Pragma("unroll")                                                       \
        for (int f = 0; f < 5; ++f) {                                           \
            _Pragma("unroll")                                                   \
            for (int o = 0; o < 4; ++o) {                                       \
                S[f][o] += C[f][o] - rng[f][SLOT][o];                           \
                rng[f][SLOT][o] = C[f][o];                                      \
            }                                                                   \
        }                                                                       \
        if (s >= 6) {                                                           \
            acc += lncc_term(S[0][0], S[1][0], S[2][0], S[3][0], S[4][0]);      \
            acc += lncc_term(S[0][1], S[1][1], S[2][1], S[3][1], S[4][1]);      \
            acc += lncc_term(S[0][2], S[1][2], S[2][2], S[3][2], S[4][2]);      \
            acc += lncc_term(S[0][3], S[1][3], S[2][3], S[3][3], S[4][3]);      \
        }                                                                       \
    }                                                                           \
    ++zin; ++s; p ^= 1; }

    // 22 steps = 3 x 7 (rolled groups, static ring slots) + 1 peeled (slot 0)
#pragma unroll 1
    for (int g = 0; g < 3; ++g) {
        STEP(0) STEP(1) STEP(2) STEP(3) STEP(4) STEP(5) STEP(6)
    }
    STEP(0)
#undef STEP

    // ---------- block reduce -> one atomic ----------
#pragma unroll
    for (int off = 32; off > 0; off >>= 1)
        acc += __shfl_down(acc, off, 64);
    if ((tid & 63) == 0) wsum[tid >> 6] = acc;
    __syncthreads();
    if (tid == 0) {
        float t = wsum[0] + wsum[1] + wsum[2] + wsum[3];
        atomicAdd(out, t * (-1.0f / NTOT));
    }
}

extern "C" void kernel_launch(void* const* d_in, const int* in_sizes, int n_in,
                              void* d_out, int out_size, void* d_ws, size_t ws_size,
                              hipStream_t stream) {
    const float* I = (const float*)d_in[0];
    const float* J = (const float*)d_in[1];
    float* out = (float*)d_out;

    hipMemsetAsync(out, 0, sizeof(float), stream);

    dim3 grid(DIM / TW, DIM / TH, 2 * NCHUNK);   // 5 x 5 x 20 = 500 blocks
    dim3 block(256);
    lncc_fused_kernel<<<grid, block, 0, stream>>>(I, J, out);
}